// Round 1
// baseline (149.477 us; speedup 1.0000x reference)
//
#include <hip/hip_runtime.h>

#define B_ 64
#define NB_ 8
#define Q_ 32
#define T_ 256
#define D_ 256
#define NBINS 11

typedef __attribute__((ext_vector_type(8))) short bf16x8;
typedef __attribute__((ext_vector_type(4))) float f32x4;
typedef unsigned short ushort_t;
typedef unsigned int uint_t;

// ws byte offsets: fragment-ordered bf16 hi/lo split of can + attn weights.
#define CANH_OFF 0u
#define CANL_OFF 8388608u
#define ATTN_OFF 16777216u  // 512 floats: softmax attention weights per (b,nb)

__device__ inline ushort_t bf16_rnd(float f) {
  uint_t u = __float_as_uint(f);
  return (ushort_t)((u + 0x8000u) >> 16);
}
__device__ inline uint_t pack2(ushort_t a, ushort_t b) {
  return (uint_t)a | ((uint_t)b << 16);
}

// ---------------------------------------------------------------------------
// kern_bins: Gaussian soft-binning via multiplicative recurrence.
// For equally-spaced mus (0.2 apart, sigma=0.1):
//   K_{j+1} = K_j * e^{-20 v} * e^{20 mu_j - 2}
// Anchor at mu=0.1 (idx 5): (v-0.1)^2 <= 1.21 for v in [-1,1], so the anchor
// K >= e^{-60.5} never underflows; every chain step lands exactly on a true
// kernel value (<= 1) so no intermediate overflows (bounded by e^{20}).
// Tails that underflow to 0 correspond to true values below the 1e-10 clip.
// 4 transcendentals instead of 11; ~5-mul chain => ~3e-7 relative error,
// crushed by log()*0.01 downstream.
// ---------------------------------------------------------------------------
__device__ inline void kern_bins(float v, float mk, float* acc) {
  // bin 0: exact-match (sigma=1e-3), computed directly as before
  float d0 = v - 1.0f;
  acc[0] += mk * exp2f(d0 * d0 * -721347.52f);  // -5e5 * log2(e)
  // anchor: mu=0.1 (idx 5)
  float t = v - 0.1f;
  float K = mk * exp2f(t * t * -72.134752f);  // -50 * log2(e)
  acc[5] += K;
  float x = v * 28.853901f;  // 20 * log2(e)
  float eu = exp2f(x);       // e^{+20v}
  float ed = exp2f(-x);      // e^{-20v}
  const float E4 = 1.8315639e-2f;   // e^-4
  const float E8 = 3.3546262e-4f;   // e^-8
  const float E12 = 6.1442124e-6f;  // e^-12
  const float E16 = 1.1253517e-7f;  // e^-16
  // downward: mu 0.1 -> -0.1 ... -0.9 (ratio const: e^0, e^-4, e^-8, ...)
  float kd = K * ed;        acc[6] += kd;
  kd = kd * ed * E4;        acc[7] += kd;
  kd = kd * ed * E8;        acc[8] += kd;
  kd = kd * ed * E12;       acc[9] += kd;
  kd = kd * ed * E16;       acc[10] += kd;
  // upward: mu 0.1 -> 0.3 ... 0.9
  float ku = K * eu * E4;   acc[4] += ku;
  ku = ku * eu * E8;        acc[3] += ku;
  ku = ku * eu * E12;       acc[2] += ku;
  ku = ku * eu * E16;       acc[1] += ku;
}

// ---------------------------------------------------------------------------
// split_kernel (R8-validated core): can row-norm + hi/lo bf16 split ->
// fragment-ordered ws. Grid 512 = (b 64, 32-row chunk 8). Zeroes out[64].
// NEW: ch==0 blocks additionally compute the input-only attention path
// (qproj = rep_cur @ W_att, 8 scores, masked softmax) once per b and store
// the 8 attn weights to ws -- removing the 512-way duplicated W_att loop
// (134 MB of L2 reads + a 256-FMA serial chain) from pool_kernel. The qproj
// tail on 64/512 blocks hides under the store drain of the streaming phase.
// ---------------------------------------------------------------------------
__global__ __launch_bounds__(256) void split_kernel(
    const float* __restrict__ can, uint4* __restrict__ canH,
    uint4* __restrict__ canL, const float* __restrict__ rep,
    const float* __restrict__ rep_cur, const float* __restrict__ mask_session,
    const float* __restrict__ W_att, const float* __restrict__ b_att,
    float* __restrict__ attn_out, float* __restrict__ out) {
  __shared__ __align__(16) ushort_t sm_hi[32 * 264];
  __shared__ __align__(16) ushort_t sm_lo[32 * 264];
  __shared__ float qp_sm[256];
  __shared__ float sc_sm[8];
  int blk = blockIdx.x;
  int tid = threadIdx.x;
  if (tid == 0 && blk < B_) out[blk] = 0.0f;
  int b = blk >> 3, ch = blk & 7;
  const float* src = can + ((size_t)b * T_ + ch * 32) * D_;
  int tilebase = b * 16 + ch * 2;

#pragma unroll
  for (int it = 0; it < 4; it++) {
    int flat = it * 2048 + tid * 8;
    int row = flat >> 8, col = flat & 255;
    const float* p = src + row * D_ + col;
    float4 x = reinterpret_cast<const float4*>(p)[0];
    float4 y = reinterpret_cast<const float4*>(p)[1];
    float s = x.x * x.x + x.y * x.y + x.z * x.z + x.w * x.w +
              y.x * y.x + y.y * y.y + y.z * y.z + y.w * y.w;
    // 32 consecutive threads cover one 256-col row
    s += __shfl_xor(s, 1);
    s += __shfl_xor(s, 2);
    s += __shfl_xor(s, 4);
    s += __shfl_xor(s, 8);
    s += __shfl_xor(s, 16);
    float inv = 1.0f / fmaxf(sqrtf(s), 1e-10f);
    float v[8] = {x.x, x.y, x.z, x.w, y.x, y.y, y.z, y.w};
    ushort_t h[8], l[8];
#pragma unroll
    for (int j = 0; j < 8; j++) {
      float sv = v[j] * inv;
      h[j] = bf16_rnd(sv);
      float hf = __uint_as_float(((uint_t)h[j]) << 16);
      l[j] = bf16_rnd(sv - hf);
    }
    uint4 ph = {pack2(h[0], h[1]), pack2(h[2], h[3]), pack2(h[4], h[5]),
                pack2(h[6], h[7])};
    uint4 pl = {pack2(l[0], l[1]), pack2(l[2], l[3]), pack2(l[4], l[5]),
                pack2(l[6], l[7])};
    *reinterpret_cast<uint4*>(&sm_hi[row * 264 + col]) = ph;
    *reinterpret_cast<uint4*>(&sm_lo[row * 264 + col]) = pl;
  }
  __syncthreads();
  int wv = tid >> 6, lane = tid & 63;
  int tl = wv >> 1, part = wv & 1;  // tile-local 0/1, hi/lo part
  int lq = lane & 15, lk = lane >> 4;
  const ushort_t* smp = part ? sm_lo : sm_hi;
  uint4* dst = part ? canL : canH;
#pragma unroll
  for (int kk = 0; kk < 8; kk++) {
    const ushort_t* a = &smp[(tl * 16 + lq) * 264 + kk * 32 + lk * 8];
    dst[((size_t)(tilebase + tl) * 8 + kk) * 64 + lane] =
        *reinterpret_cast<const uint4*>(a);
  }

  // ---- attention path (once per b, on ch==0 blocks; block-uniform branch) --
  if (ch == 0) {
    const float* rc = rep_cur + b * D_;
    float acc2 = b_att[tid];
#pragma unroll 8
    for (int k = 0; k < D_; k++) acc2 += rc[k] * W_att[(size_t)k * D_ + tid];
    qp_sm[tid] = acc2;
    __syncthreads();
    for (int nn = wv; nn < NB_; nn += 4) {
      const float* rp = rep + ((size_t)b * NB_ + nn) * D_;
      float4 r4 = reinterpret_cast<const float4*>(rp)[lane];
      float4 q4 = *reinterpret_cast<const float4*>(&qp_sm[lane * 4]);
      float s = r4.x * q4.x + r4.y * q4.y + r4.z * q4.z + r4.w * q4.w;
#pragma unroll
      for (int off = 32; off > 0; off >>= 1) s += __shfl_down(s, off);
      if (lane == 0) sc_sm[nn] = s * 0.0625f;  // 1/sqrt(256)
    }
    __syncthreads();
    if (tid == 0) {
      float sc[NB_];
      float mx = -1e30f;
      for (int nn = 0; nn < NB_; nn++) {
        float s = (mask_session[b * NB_ + nn] > 0.f) ? sc_sm[nn] : -1e9f;
        sc[nn] = s;
        mx = fmaxf(mx, s);
      }
      float den = 0.f;
      for (int nn = 0; nn < NB_; nn++) {
        sc[nn] = __expf(sc[nn] - mx);
        den += sc[nn];
      }
      float invd = 1.0f / den;
      for (int nn = 0; nn < NB_; nn++)
        attn_out[b * NB_ + nn] = sc[nn] * invd;
    }
  }
}

// ---------------------------------------------------------------------------
// pool_kernel: R8-validated body (register A-split, barrier-free deferred-
// bins 3-MFMA pipeline, shfl+LDS reduce). Bins now use the 4-exp recurrence
// (kern_bins) instead of 11 exps per value. Epilogue reads the precomputed
// attn weight from ws instead of duplicating the W_att projection + softmax
// per block; (e) only needs wave-0-local pooled_sm, so the second
// __syncthreads is gone. 512 total atomics into out (zeroed by split_kernel).
// XCD swizzle: blockIdx%8 = b%8 -> can[b] fragments stay in one L2.
// ---------------------------------------------------------------------------
__global__ __launch_bounds__(256, 2) void pool_kernel(
    const float* __restrict__ hq, const uint4* __restrict__ canH,
    const uint4* __restrict__ canL, const float* __restrict__ mask_can,
    const float* __restrict__ word_atten, const float* __restrict__ mask_hq,
    const float* __restrict__ mask_session, const float* __restrict__ W_dense,
    const float* __restrict__ b_dense, const float* __restrict__ attn_ws,
    float* __restrict__ out) {
  // LDS: partial[704] | lp[352] | pooled[11]
  __shared__ float smbuf[1067];
  float* partial = smbuf;          // 704
  float* lp_sm = smbuf + 704;      // 352
  float* pooled_sm = smbuf + 1056; // 11

  int i = blockIdx.x;
  int b = i & 63;  // XCD = i%8 = b%8
  int nb = i >> 6;
  int outb = b * NB_ + nb;
  int tid = threadIdx.x;
  int wv = tid >> 6, lane = tid & 63;
  int lq = lane & 15, lk = lane >> 4;
  int mtile = wv & 1, tq = wv >> 1;

  // ---- A fragments: register norm + hi/lo split (R6/R8-validated) ----
  const float* arow =
      hq + (size_t)outb * (Q_ * D_) + (size_t)(mtile * 16 + lq) * D_;
  float sumsq = 0.f;
#pragma unroll
  for (int kk = 0; kk < 8; kk++) {
    const float* p = arow + kk * 32 + lk * 8;
    float4 x = reinterpret_cast<const float4*>(p)[0];
    float4 y = reinterpret_cast<const float4*>(p)[1];
    sumsq += x.x * x.x + x.y * x.y + x.z * x.z + x.w * x.w +
             y.x * y.x + y.y * y.y + y.z * y.z + y.w * y.w;
  }
  sumsq += __shfl_xor(sumsq, 16);
  sumsq += __shfl_xor(sumsq, 32);
  float ainv = 1.0f / fmaxf(sqrtf(sumsq), 1e-10f);

  bf16x8 ah[8], al[8];
#pragma unroll
  for (int kk = 0; kk < 8; kk++) {
    const float* p = arow + kk * 32 + lk * 8;  // L1-hot reload
    float4 x = reinterpret_cast<const float4*>(p)[0];
    float4 y = reinterpret_cast<const float4*>(p)[1];
    float v[8] = {x.x, x.y, x.z, x.w, y.x, y.y, y.z, y.w};
    union { bf16x8 v8; ushort_t u[8]; } H, L;
#pragma unroll
    for (int j = 0; j < 8; j++) {
      float s = v[j] * ainv;
      ushort_t h = bf16_rnd(s);
      float hf = __uint_as_float(((uint_t)h) << 16);
      H.u[j] = h;
      L.u[j] = bf16_rnd(s - hf);
    }
    ah[kk] = H.v8;
    al[kk] = L.v8;
  }

  float binacc[4][NBINS];
#pragma unroll
  for (int r = 0; r < 4; r++)
#pragma unroll
    for (int j = 0; j < NBINS; j++) binacc[r][j] = 0.0f;

  f32x4 accPrev;
  float mkPrev = 0.0f;

  {  // tile 0
    int tt = tq * 8;
    size_t bbase = (size_t)(b * 16 + tt) * 8 * 64 + lane;
    f32x4 acc = {0.f, 0.f, 0.f, 0.f};
#pragma unroll
    for (int kk = 0; kk < 8; kk++) {
      bf16x8 bh = *reinterpret_cast<const bf16x8*>(&canH[bbase + kk * 64]);
      bf16x8 bl = *reinterpret_cast<const bf16x8*>(&canL[bbase + kk * 64]);
      acc = __builtin_amdgcn_mfma_f32_16x16x32_bf16(ah[kk], bh, acc, 0, 0, 0);
      acc = __builtin_amdgcn_mfma_f32_16x16x32_bf16(al[kk], bh, acc, 0, 0, 0);
      acc = __builtin_amdgcn_mfma_f32_16x16x32_bf16(ah[kk], bl, acc, 0, 0, 0);
    }
    accPrev = acc;
    mkPrev = mask_can[b * T_ + tt * 16 + lq];
  }

  for (int ti = 1; ti < 8; ti++) {  // load(ti) issued before bins(ti-1)
    int tt = tq * 8 + ti;
    size_t bbase = (size_t)(b * 16 + tt) * 8 * 64 + lane;
    bf16x8 bh[8], bl[8];
#pragma unroll
    for (int kk = 0; kk < 8; kk++) {
      bh[kk] = *reinterpret_cast<const bf16x8*>(&canH[bbase + kk * 64]);
      bl[kk] = *reinterpret_cast<const bf16x8*>(&canL[bbase + kk * 64]);
    }
    // C/D: col(t)=lane&15, row(q)=(lane>>4)*4+reg  [R4-validated]
#pragma unroll
    for (int r = 0; r < 4; r++) kern_bins(accPrev[r], mkPrev, binacc[r]);
    f32x4 acc = {0.f, 0.f, 0.f, 0.f};
#pragma unroll
    for (int kk = 0; kk < 8; kk++) {
      acc = __builtin_amdgcn_mfma_f32_16x16x32_bf16(ah[kk], bh[kk], acc, 0, 0, 0);
      acc = __builtin_amdgcn_mfma_f32_16x16x32_bf16(al[kk], bh[kk], acc, 0, 0, 0);
      acc = __builtin_amdgcn_mfma_f32_16x16x32_bf16(ah[kk], bl[kk], acc, 0, 0, 0);
    }
    accPrev = acc;
    mkPrev = mask_can[b * T_ + tt * 16 + lq];
  }
#pragma unroll
  for (int r = 0; r < 4; r++)  // bins of last tile
    kern_bins(accPrev[r], mkPrev, binacc[r]);

  // ---- reduce over the 16 t-cols (lq) held by this wave ----
#pragma unroll
  for (int r = 0; r < 4; r++)
#pragma unroll
    for (int j = 0; j < NBINS; j++) {
      float v = binacc[r][j];
      v += __shfl_xor(v, 1);
      v += __shfl_xor(v, 2);
      v += __shfl_xor(v, 4);
      v += __shfl_xor(v, 8);
      binacc[r][j] = v;
    }
  if (lq == 0) {
#pragma unroll
    for (int r = 0; r < 4; r++)
#pragma unroll
      for (int j = 0; j < NBINS; j++)
        partial[(wv * 16 + lk * 4 + r) * NBINS + j] = binacc[r][j];
  }
  __syncthreads();

  // ---- in-block epilogue ----
  // (a) combine tq halves + log-pool * word_atten * mask_hq -> lp_sm.
  //     STRIDED over 352 items (R3 lesson).
  for (int idx = tid; idx < Q_ * NBINS; idx += 256) {
    int q = idx / NBINS;
    int j = idx - q * NBINS;
    int m = q >> 4, r16 = q & 15;
    float sum = partial[(m * 16 + r16) * NBINS + j] +
                partial[((2 + m) * 16 + r16) * NBINS + j];
    float wa = word_atten[outb * Q_ + q] * mask_hq[outb * Q_ + q];
    lp_sm[idx] = logf(fmaxf(sum, 1e-10f)) * 0.01f * wa;
  }
  __syncthreads();

  // (b) pooled[j] = sum_q lp; then tid 0 finishes. pooled_sm is written and
  // read entirely within wave 0 (lanes 0..10 -> lane 0), wave-synchronous on
  // CDNA (program-ordered ds ops) -- no second barrier needed.
  if (tid < NBINS) {
    float s = 0.f;
#pragma unroll
    for (int q = 0; q < Q_; q++) s += lp_sm[q * NBINS + tid];
    pooled_sm[tid] = s;
  }
  if (tid == 0) {
    float ms = mask_session[outb];
    float pw = b_dense[0];
#pragma unroll
    for (int j = 0; j < NBINS; j++) pw += pooled_sm[j] * ms * W_dense[j];
    float res = tanhf(pw) * attn_ws[outb];  // attn precomputed by split_kernel
    atomicAdd(&out[b], res);  // 512 total atomics; out zeroed by split_kernel
  }
}

// ---------------------------------------------------------------------------
// ws: canH/canL (16.8 MB) + attn[512]. 2 dispatches; no psum, no fences.
// ---------------------------------------------------------------------------
extern "C" void kernel_launch(void* const* d_in, const int* in_sizes, int n_in,
                              void* d_out, int out_size, void* d_ws,
                              size_t ws_size, hipStream_t stream) {
  const float* word_atten = (const float*)d_in[0];
  const float* hq = (const float*)d_in[1];
  const float* can = (const float*)d_in[2];
  const float* rep = (const float*)d_in[3];
  const float* rep_cur = (const float*)d_in[4];
  const float* mask_hq = (const float*)d_in[5];
  const float* mask_can = (const float*)d_in[6];
  const float* mask_session = (const float*)d_in[7];
  const float* W_dense = (const float*)d_in[8];
  const float* b_dense = (const float*)d_in[9];
  const float* W_att = (const float*)d_in[10];
  const float* b_att = (const float*)d_in[11];
  float* out = (float*)d_out;

  char* ws = (char*)d_ws;
  uint4* canH = (uint4*)(ws + CANH_OFF);
  uint4* canL = (uint4*)(ws + CANL_OFF);
  float* attn_ws = (float*)(ws + ATTN_OFF);

  hipLaunchKernelGGL(split_kernel, dim3(512), dim3(256), 0, stream, can, canH,
                     canL, rep, rep_cur, mask_session, W_att, b_att, attn_ws,
                     out);
  hipLaunchKernelGGL(pool_kernel, dim3(B_ * NB_), dim3(256), 0, stream, hq,
                     canH, canL, mask_can, word_atten, mask_hq, mask_session,
                     W_dense, b_dense, attn_ws, out);
}

// Round 2
// 147.526 us; speedup vs baseline: 1.0132x; 1.0132x over previous
//
#include <hip/hip_runtime.h>

#define B_ 64
#define NB_ 8
#define Q_ 32
#define T_ 256
#define D_ 256
#define NBINS 11

typedef __attribute__((ext_vector_type(8))) short bf16x8;
typedef __attribute__((ext_vector_type(4))) float f32x4;
typedef unsigned short ushort_t;
typedef unsigned int uint_t;

// ws byte offsets: fragment-ordered bf16 hi/lo split of can. Nothing else.
#define CANH_OFF 0u
#define CANL_OFF 8388608u

__device__ inline ushort_t bf16_rnd(float f) {
  uint_t u = __float_as_uint(f);
  return (ushort_t)((u + 0x8000u) >> 16);
}
__device__ inline uint_t pack2(ushort_t a, ushort_t b) {
  return (uint_t)a | ((uint_t)b << 16);
}

// ---------------------------------------------------------------------------
// split_kernel (R8-validated, reverted to R0 form): can row-norm + hi/lo bf16
// split -> fragment-ordered ws. Grid 512 = (b 64, 32-row chunk 8). Also
// zeroes out[64] for the pool kernel's atomicAdd accumulation.
// (R11 lesson: hoisting the W_att/softmax path here cost +17us -- the ch==0
// qproj serial chain became the kernel's critical path. Reverted.)
// ---------------------------------------------------------------------------
__global__ __launch_bounds__(256) void split_kernel(
    const float* __restrict__ can, uint4* __restrict__ canH,
    uint4* __restrict__ canL, float* __restrict__ out) {
  __shared__ __align__(16) ushort_t sm_hi[32 * 264];
  __shared__ __align__(16) ushort_t sm_lo[32 * 264];
  int blk = blockIdx.x;
  int tid = threadIdx.x;
  if (tid == 0 && blk < B_) out[blk] = 0.0f;
  int b = blk >> 3, ch = blk & 7;
  const float* src = can + ((size_t)b * T_ + ch * 32) * D_;
  int tilebase = b * 16 + ch * 2;

#pragma unroll
  for (int it = 0; it < 4; it++) {
    int flat = it * 2048 + tid * 8;
    int row = flat >> 8, col = flat & 255;
    const float* p = src + row * D_ + col;
    float4 x = reinterpret_cast<const float4*>(p)[0];
    float4 y = reinterpret_cast<const float4*>(p)[1];
    float s = x.x * x.x + x.y * x.y + x.z * x.z + x.w * x.w +
              y.x * y.x + y.y * y.y + y.z * y.z + y.w * y.w;
    // 32 consecutive threads cover one 256-col row
    s += __shfl_xor(s, 1);
    s += __shfl_xor(s, 2);
    s += __shfl_xor(s, 4);
    s += __shfl_xor(s, 8);
    s += __shfl_xor(s, 16);
    float inv = 1.0f / fmaxf(sqrtf(s), 1e-10f);
    float v[8] = {x.x, x.y, x.z, x.w, y.x, y.y, y.z, y.w};
    ushort_t h[8], l[8];
#pragma unroll
    for (int j = 0; j < 8; j++) {
      float sv = v[j] * inv;
      h[j] = bf16_rnd(sv);
      float hf = __uint_as_float(((uint_t)h[j]) << 16);
      l[j] = bf16_rnd(sv - hf);
    }
    uint4 ph = {pack2(h[0], h[1]), pack2(h[2], h[3]), pack2(h[4], h[5]),
                pack2(h[6], h[7])};
    uint4 pl = {pack2(l[0], l[1]), pack2(l[2], l[3]), pack2(l[4], l[5]),
                pack2(l[6], l[7])};
    *reinterpret_cast<uint4*>(&sm_hi[row * 264 + col]) = ph;
    *reinterpret_cast<uint4*>(&sm_lo[row * 264 + col]) = pl;
  }
  __syncthreads();
  int wv = tid >> 6, lane = tid & 63;
  int tl = wv >> 1, part = wv & 1;  // tile-local 0/1, hi/lo part
  int lq = lane & 15, lk = lane >> 4;
  const ushort_t* smp = part ? sm_lo : sm_hi;
  uint4* dst = part ? canL : canH;
#pragma unroll
  for (int kk = 0; kk < 8; kk++) {
    const ushort_t* a = &smp[(tl * 16 + lq) * 264 + kk * 32 + lk * 8];
    dst[((size_t)(tilebase + tl) * 8 + kk) * 64 + lane] =
        *reinterpret_cast<const uint4*>(a);
  }
}

// ---------------------------------------------------------------------------
// pool_kernel: R8-validated body (register A-split, barrier-free deferred-
// bins 3-MFMA pipeline, 11 independent exps, shfl+LDS reduce, self-contained
// epilogue) restructured for OCCUPANCY:
//   R11 counters: dur 44.5us with MfmaUtil 4.9 / VALUBusy 18.8 / HBM 4.7 /
//   Occupancy 18.8 -> latency-bound; grid 512x4waves = only 2 waves/SIMD.
//   Fix: 512 threads (8 waves), each wave covers 4 t-tiles (64 t) instead of
//   8, __launch_bounds__(512,4) -> 16 waves/CU (4/SIMD), VGPR cap 128 (~84
//   used). Work per wave halves; wave count doubles; stalls interleave.
// Also: mask_can loads hoisted out of the tile loop (they were on the serial
// bins dependency chain).
// XCD swizzle: blockIdx%8 = b%8 -> can[b] fragments stay in one L2.
// ---------------------------------------------------------------------------
__global__ __launch_bounds__(512, 4) void pool_kernel(
    const float* __restrict__ hq, const uint4* __restrict__ canH,
    const uint4* __restrict__ canL, const float* __restrict__ mask_can,
    const float* __restrict__ word_atten, const float* __restrict__ mask_hq,
    const float* __restrict__ rep, const float* __restrict__ rep_cur,
    const float* __restrict__ mask_session, const float* __restrict__ W_dense,
    const float* __restrict__ b_dense, const float* __restrict__ W_att,
    const float* __restrict__ b_att, float* __restrict__ out) {
  // LDS: partial[1408] | lp[352] | qproj[256] | scores[8] | pooled[11]
  __shared__ float smbuf[2035];
  float* partial = smbuf;            // 1408 (8 waves x 16 q x 11)
  float* lp_sm = smbuf + 1408;       // 352
  float* qproj = smbuf + 1760;       // 256
  float* scores_sm = smbuf + 2016;   // 8
  float* pooled_sm = smbuf + 2024;   // 11

  const float mus[NBINS] = {1.0f, 0.9f, 0.7f, 0.5f, 0.3f, 0.1f,
                            -0.1f, -0.3f, -0.5f, -0.7f, -0.9f};
  const float nis2[NBINS] = {-5.0e5f, -50.f, -50.f, -50.f, -50.f, -50.f,
                             -50.f, -50.f, -50.f, -50.f, -50.f};

  int i = blockIdx.x;
  int b = i & 63;  // XCD = i%8 = b%8
  int nb = i >> 6;
  int outb = b * NB_ + nb;
  int tid = threadIdx.x;
  int wv = tid >> 6, lane = tid & 63;
  int lq = lane & 15, lk = lane >> 4;
  int mtile = wv & 1, tq = wv >> 1;  // mtile: q-tile 0/1; tq: t-quarter 0..3

  // ---- A fragments: register norm + hi/lo split (R6/R8-validated) ----
  const float* arow =
      hq + (size_t)outb * (Q_ * D_) + (size_t)(mtile * 16 + lq) * D_;
  float sumsq = 0.f;
#pragma unroll
  for (int kk = 0; kk < 8; kk++) {
    const float* p = arow + kk * 32 + lk * 8;
    float4 x = reinterpret_cast<const float4*>(p)[0];
    float4 y = reinterpret_cast<const float4*>(p)[1];
    sumsq += x.x * x.x + x.y * x.y + x.z * x.z + x.w * x.w +
             y.x * y.x + y.y * y.y + y.z * y.z + y.w * y.w;
  }
  sumsq += __shfl_xor(sumsq, 16);
  sumsq += __shfl_xor(sumsq, 32);
  float ainv = 1.0f / fmaxf(sqrtf(sumsq), 1e-10f);

  bf16x8 ah[8], al[8];
#pragma unroll
  for (int kk = 0; kk < 8; kk++) {
    const float* p = arow + kk * 32 + lk * 8;  // L1-hot reload
    float4 x = reinterpret_cast<const float4*>(p)[0];
    float4 y = reinterpret_cast<const float4*>(p)[1];
    float v[8] = {x.x, x.y, x.z, x.w, y.x, y.y, y.z, y.w};
    union { bf16x8 v8; ushort_t u[8]; } H, L;
#pragma unroll
    for (int j = 0; j < 8; j++) {
      float s = v[j] * ainv;
      ushort_t h = bf16_rnd(s);
      float hf = __uint_as_float(((uint_t)h) << 16);
      H.u[j] = h;
      L.u[j] = bf16_rnd(s - hf);
    }
    ah[kk] = H.v8;
    al[kk] = L.v8;
  }

  // ---- hoisted mask loads (were on the serial bins dependency chain) ----
  float mk4[4];
#pragma unroll
  for (int ti = 0; ti < 4; ti++)
    mk4[ti] = mask_can[b * T_ + (tq * 4 + ti) * 16 + lq];

  float binacc[4][NBINS];
#pragma unroll
  for (int r = 0; r < 4; r++)
#pragma unroll
    for (int j = 0; j < NBINS; j++) binacc[r][j] = 0.0f;

  f32x4 accPrev;
  float mkPrev = 0.0f;

  {  // tile 0
    int tt = tq * 4;
    size_t bbase = (size_t)(b * 16 + tt) * 8 * 64 + lane;
    f32x4 acc = {0.f, 0.f, 0.f, 0.f};
#pragma unroll
    for (int kk = 0; kk < 8; kk++) {
      bf16x8 bh = *reinterpret_cast<const bf16x8*>(&canH[bbase + kk * 64]);
      bf16x8 bl = *reinterpret_cast<const bf16x8*>(&canL[bbase + kk * 64]);
      acc = __builtin_amdgcn_mfma_f32_16x16x32_bf16(ah[kk], bh, acc, 0, 0, 0);
      acc = __builtin_amdgcn_mfma_f32_16x16x32_bf16(al[kk], bh, acc, 0, 0, 0);
      acc = __builtin_amdgcn_mfma_f32_16x16x32_bf16(ah[kk], bl, acc, 0, 0, 0);
    }
    accPrev = acc;
    mkPrev = mk4[0];
  }

  for (int ti = 1; ti < 4; ti++) {  // load(ti) issued before bins(ti-1)
    int tt = tq * 4 + ti;
    size_t bbase = (size_t)(b * 16 + tt) * 8 * 64 + lane;
    bf16x8 bh[8], bl[8];
#pragma unroll
    for (int kk = 0; kk < 8; kk++) {
      bh[kk] = *reinterpret_cast<const bf16x8*>(&canH[bbase + kk * 64]);
      bl[kk] = *reinterpret_cast<const bf16x8*>(&canL[bbase + kk * 64]);
    }
    // C/D: col(t)=lane&15, row(q)=(lane>>4)*4+reg  [R4-validated]
#pragma unroll
    for (int r = 0; r < 4; r++) {
      float v0 = accPrev[r];
#pragma unroll
      for (int j = 0; j < NBINS; j++) {
        float d0 = v0 - mus[j];
        binacc[r][j] += mkPrev * __expf(d0 * d0 * nis2[j]);
      }
    }
    f32x4 acc = {0.f, 0.f, 0.f, 0.f};
#pragma unroll
    for (int kk = 0; kk < 8; kk++) {
      acc = __builtin_amdgcn_mfma_f32_16x16x32_bf16(ah[kk], bh[kk], acc, 0, 0, 0);
      acc = __builtin_amdgcn_mfma_f32_16x16x32_bf16(al[kk], bh[kk], acc, 0, 0, 0);
      acc = __builtin_amdgcn_mfma_f32_16x16x32_bf16(ah[kk], bl[kk], acc, 0, 0, 0);
    }
    accPrev = acc;
    mkPrev = mk4[ti];
  }
#pragma unroll
  for (int r = 0; r < 4; r++) {  // bins of last tile
    float v0 = accPrev[r];
#pragma unroll
    for (int j = 0; j < NBINS; j++) {
      float d0 = v0 - mus[j];
      binacc[r][j] += mkPrev * __expf(d0 * d0 * nis2[j]);
    }
  }

  // ---- reduce over the 16 t-cols (lq) held by this wave ----
#pragma unroll
  for (int r = 0; r < 4; r++)
#pragma unroll
    for (int j = 0; j < NBINS; j++) {
      float v = binacc[r][j];
      v += __shfl_xor(v, 1);
      v += __shfl_xor(v, 2);
      v += __shfl_xor(v, 4);
      v += __shfl_xor(v, 8);
      binacc[r][j] = v;
    }
  if (lq == 0) {
#pragma unroll
    for (int r = 0; r < 4; r++)
#pragma unroll
      for (int j = 0; j < NBINS; j++)
        partial[(wv * 16 + lk * 4 + r) * NBINS + j] = binacc[r][j];
  }
  __syncthreads();

  // ---- in-block epilogue (no global round-trip) ----
  // (a) combine the 4 tq quarters + log-pool * word_atten * mask_hq -> lp_sm.
  //     wv encodes (mtile,tq): row (tq*2+m)*16 + r16.
  for (int idx = tid; idx < Q_ * NBINS; idx += 512) {
    int q = idx / NBINS;
    int j = idx - q * NBINS;
    int m = q >> 4, r16 = q & 15;
    float sum = partial[((0 + m) * 16 + r16) * NBINS + j] +
                partial[((2 + m) * 16 + r16) * NBINS + j] +
                partial[((4 + m) * 16 + r16) * NBINS + j] +
                partial[((6 + m) * 16 + r16) * NBINS + j];
    float wa = word_atten[outb * Q_ + q] * mask_hq[outb * Q_ + q];
    lp_sm[idx] = logf(fmaxf(sum, 1e-10f)) * 0.01f * wa;
  }

  // (b) W_att projection (input-only; duplicated across the 8 nb-blocks of b)
  if (tid < D_) {
    const float* rc = rep_cur + b * D_;
    float acc2 = b_att[tid];
    for (int k = 0; k < D_; k++) acc2 += rc[k] * W_att[k * D_ + tid];
    qproj[tid] = acc2;
  }
  __syncthreads();

  // (c) pooled[j] = sum_q lp (this block's nb only)
  if (tid < NBINS) {
    float s = 0.f;
#pragma unroll
    for (int q = 0; q < Q_; q++) s += lp_sm[q * NBINS + tid];
    pooled_sm[tid] = s;
  }

  // (d) all 8 attention scores (one per wave)
  if (wv < NB_) {
    int nn = wv;
    const float* rp = rep + ((size_t)b * NB_ + nn) * D_;
    float4 r4 = reinterpret_cast<const float4*>(rp)[lane];
    float4 q4 = *reinterpret_cast<float4*>(&qproj[lane * 4]);
    float s = r4.x * q4.x + r4.y * q4.y + r4.z * q4.z + r4.w * q4.w;
#pragma unroll
    for (int off = 32; off > 0; off >>= 1) s += __shfl_down(s, off);
    if (lane == 0) scores_sm[nn] = s * 0.0625f;  // 1/sqrt(256)
  }
  __syncthreads();

  // (e) masked softmax (local, deterministic) + this nb's contribution
  if (tid == 0) {
    float sc[NB_];
    float mx = -1e30f;
    for (int nn = 0; nn < NB_; nn++) {
      float s = (mask_session[b * NB_ + nn] > 0.f) ? scores_sm[nn] : -1e9f;
      sc[nn] = s;
      mx = fmaxf(mx, s);
    }
    float den = 0.f;
    for (int nn = 0; nn < NB_; nn++) {
      sc[nn] = __expf(sc[nn] - mx);
      den += sc[nn];
    }
    float ms = mask_session[b * NB_ + nb];
    float pw = b_dense[0];
#pragma unroll
    for (int j = 0; j < NBINS; j++) pw += pooled_sm[j] * ms * W_dense[j];
    float res = tanhf(pw) * (sc[nb] / den);
    atomicAdd(&out[b], res);  // 512 total atomics; out zeroed by split_kernel
  }
}

// ---------------------------------------------------------------------------
// ws: canH/canL only (16.8 MB). 2 dispatches total; no psum, no fences.
// ---------------------------------------------------------------------------
extern "C" void kernel_launch(void* const* d_in, const int* in_sizes, int n_in,
                              void* d_out, int out_size, void* d_ws,
                              size_t ws_size, hipStream_t stream) {
  const float* word_atten = (const float*)d_in[0];
  const float* hq = (const float*)d_in[1];
  const float* can = (const float*)d_in[2];
  const float* rep = (const float*)d_in[3];
  const float* rep_cur = (const float*)d_in[4];
  const float* mask_hq = (const float*)d_in[5];
  const float* mask_can = (const float*)d_in[6];
  const float* mask_session = (const float*)d_in[7];
  const float* W_dense = (const float*)d_in[8];
  const float* b_dense = (const float*)d_in[9];
  const float* W_att = (const float*)d_in[10];
  const float* b_att = (const float*)d_in[11];
  float* out = (float*)d_out;

  char* ws = (char*)d_ws;
  uint4* canH = (uint4*)(ws + CANH_OFF);
  uint4* canL = (uint4*)(ws + CANL_OFF);

  hipLaunchKernelGGL(split_kernel, dim3(512), dim3(256), 0, stream, can, canH,
                     canL, out);
  hipLaunchKernelGGL(pool_kernel, dim3(B_ * NB_), dim3(512), 0, stream, hq,
                     canH, canL, mask_can, word_atten, mask_hq, rep, rep_cur,
                     mask_session, W_dense, b_dense, W_att, b_att, out);
}

// Round 3
// 139.726 us; speedup vs baseline: 1.0698x; 1.0558x over previous
//
#include <hip/hip_runtime.h>

#define B_ 64
#define NB_ 8
#define Q_ 32
#define T_ 256
#define D_ 256
#define NBINS 11

typedef __attribute__((ext_vector_type(8))) short bf16x8;
typedef __attribute__((ext_vector_type(4))) float f32x4;
typedef unsigned short ushort_t;
typedef unsigned int uint_t;

// ws byte offsets: fragment-ordered bf16 hi/lo of can (B-side) and hq
// (A-side), + per-(outb,ts) bin partial sums.
#define CANH_OFF 0u          //  8 MB: 64b x 16 tiles x 8 kk x 64 lanes x 16B
#define CANL_OFF 8388608u    //  8 MB
#define HQH_OFF 16777216u    //  8 MB: 512 outb x 2 mtile x 8 kk x 64 x 16B
#define HQL_OFF 25165824u    //  8 MB
#define PSUM_OFF 33554432u   //  2.8 MB: 2048 blocks x 352 floats

__device__ inline ushort_t bf16_rnd(float f) {
  uint_t u = __float_as_uint(f);
  return (ushort_t)((u + 0x8000u) >> 16);
}
__device__ inline uint_t pack2(ushort_t a, ushort_t b) {
  return (uint_t)a | ((uint_t)b << 16);
}

// 11 independent exps (R0-validated form; R1's serial recurrence reverted).
__device__ inline void bins_acc(f32x4 acc, float mk, float binacc[4][NBINS]) {
  const float mus[NBINS] = {1.0f, 0.9f, 0.7f, 0.5f, 0.3f, 0.1f,
                            -0.1f, -0.3f, -0.5f, -0.7f, -0.9f};
  const float nis2[NBINS] = {-5.0e5f, -50.f, -50.f, -50.f, -50.f, -50.f,
                             -50.f, -50.f, -50.f, -50.f, -50.f};
#pragma unroll
  for (int r = 0; r < 4; r++) {
    float v0 = acc[r];
#pragma unroll
    for (int j = 0; j < NBINS; j++) {
      float d0 = v0 - mus[j];
      binacc[r][j] += mk * __expf(d0 * d0 * nis2[j]);
    }
  }
}

// ---------------------------------------------------------------------------
// split_kernel: row-norm + hi/lo bf16 split -> fragment-ordered ws, for BOTH
// can (blocks 0..511: b=blk>>3, ch=blk&7, 32 rows) and hq (blocks 512..1023:
// outb=blk-512, its 32 q-rows). Identical streaming body (R8-validated);
// only src/dst/tilebase differ. Grid 1024.
// Rationale (R12): pre-converting hq removes the norm/convert dependency
// chain from pool's start AND avoids duplicating A-prep across pool's new
// 4-way t-split. Same total conversion work, done once, bandwidth-bound.
// ---------------------------------------------------------------------------
__global__ __launch_bounds__(256) void split_kernel(
    const float* __restrict__ can, const float* __restrict__ hq,
    uint4* __restrict__ canH, uint4* __restrict__ canL,
    uint4* __restrict__ hqH, uint4* __restrict__ hqL) {
  __shared__ __align__(16) ushort_t sm_hi[32 * 264];
  __shared__ __align__(16) ushort_t sm_lo[32 * 264];
  int blk = blockIdx.x;
  int tid = threadIdx.x;
  const float* src;
  uint4 *dH, *dL;
  int tilebase;
  if (blk < 512) {
    int b = blk >> 3, ch = blk & 7;
    src = can + ((size_t)b * T_ + ch * 32) * D_;
    dH = canH;
    dL = canL;
    tilebase = b * 16 + ch * 2;
  } else {
    int outb = blk - 512;
    src = hq + (size_t)outb * (Q_ * D_);
    dH = hqH;
    dL = hqL;
    tilebase = outb * 2;
  }

#pragma unroll
  for (int it = 0; it < 4; it++) {
    int flat = it * 2048 + tid * 8;
    int row = flat >> 8, col = flat & 255;
    const float* p = src + row * D_ + col;
    float4 x = reinterpret_cast<const float4*>(p)[0];
    float4 y = reinterpret_cast<const float4*>(p)[1];
    float s = x.x * x.x + x.y * x.y + x.z * x.z + x.w * x.w +
              y.x * y.x + y.y * y.y + y.z * y.z + y.w * y.w;
    // 32 consecutive threads cover one 256-col row
    s += __shfl_xor(s, 1);
    s += __shfl_xor(s, 2);
    s += __shfl_xor(s, 4);
    s += __shfl_xor(s, 8);
    s += __shfl_xor(s, 16);
    float inv = 1.0f / fmaxf(sqrtf(s), 1e-10f);
    float v[8] = {x.x, x.y, x.z, x.w, y.x, y.y, y.z, y.w};
    ushort_t h[8], l[8];
#pragma unroll
    for (int j = 0; j < 8; j++) {
      float sv = v[j] * inv;
      h[j] = bf16_rnd(sv);
      float hf = __uint_as_float(((uint_t)h[j]) << 16);
      l[j] = bf16_rnd(sv - hf);
    }
    uint4 ph = {pack2(h[0], h[1]), pack2(h[2], h[3]), pack2(h[4], h[5]),
                pack2(h[6], h[7])};
    uint4 pl = {pack2(l[0], l[1]), pack2(l[2], l[3]), pack2(l[4], l[5]),
                pack2(l[6], l[7])};
    *reinterpret_cast<uint4*>(&sm_hi[row * 264 + col]) = ph;
    *reinterpret_cast<uint4*>(&sm_lo[row * 264 + col]) = pl;
  }
  __syncthreads();
  int wv = tid >> 6, lane = tid & 63;
  int tl = wv >> 1, part = wv & 1;  // tile-local 0/1, hi/lo part
  int lq = lane & 15, lk = lane >> 4;
  const ushort_t* smp = part ? sm_lo : sm_hi;
  uint4* dst = part ? dL : dH;
#pragma unroll
  for (int kk = 0; kk < 8; kk++) {
    const ushort_t* a = &smp[(tl * 16 + lq) * 264 + kk * 32 + lk * 8];
    dst[((size_t)(tilebase + tl) * 8 + kk) * 64 + lane] =
        *reinterpret_cast<const uint4*>(a);
  }
}

// ---------------------------------------------------------------------------
// pool_kernel: R0-validated per-wave inner structure (full bh/bl prefetch,
// 3-MFMA hi/lo chain, deferred bins, shfl+LDS reduce) with a 4-way t-split
// across blocks for occupancy/MLP:
//   R11/R12 counters: pool was ~90% stall (MfmaUtil<5, VALUBusy~20, HBM<5%)
//   at 2 blocks/CU -- grid-limited MLP. R12's in-block wave doubling spilled
//   (VGPR 60 < live set) and regressed; this keeps the wave structure intact
//   and adds BLOCKS instead: grid 2048 = (b, nb, ts), 8 blocks/CU possible.
// A-fragments are now preloaded from ws (split pre-converted them).
// Writes 352 bin partials per block to psum; NO epilogue here.
// XCD: i%8 = b%8, so all 32 blocks of a given b share one L2.
// ---------------------------------------------------------------------------
__global__ __launch_bounds__(256, 2) void pool_kernel(
    const uint4* __restrict__ hqH, const uint4* __restrict__ hqL,
    const uint4* __restrict__ canH, const uint4* __restrict__ canL,
    const float* __restrict__ mask_can, float* __restrict__ psum) {
  __shared__ float partial[4 * 16 * NBINS];  // 704

  int i = blockIdx.x;
  int b = i & 63;           // XCD = i%8 = b%8
  int rest = i >> 6;        // 0..31
  int nb = rest & 7, ts = rest >> 3;
  int outb = b * NB_ + nb;
  int tid = threadIdx.x;
  int wv = tid >> 6, lane = tid & 63;
  int lq = lane & 15, lk = lane >> 4;
  int mtile = wv & 1, tq = wv >> 1;  // q-tile 0/1, t-pair 0/1

  // ---- A fragments: straight 16B loads (pre-converted by split) ----
  bf16x8 ah[8], al[8];
  size_t abase = (size_t)(outb * 2 + mtile) * 512 + lane;
#pragma unroll
  for (int kk = 0; kk < 8; kk++) {
    ah[kk] = *reinterpret_cast<const bf16x8*>(&hqH[abase + kk * 64]);
    al[kk] = *reinterpret_cast<const bf16x8*>(&hqL[abase + kk * 64]);
  }

  int t0 = ts * 4 + tq * 2;  // this wave's two tiles: t0, t0+1
  float mk0 = mask_can[b * T_ + (t0 + 0) * 16 + lq];
  float mk1 = mask_can[b * T_ + (t0 + 1) * 16 + lq];

  float binacc[4][NBINS];
#pragma unroll
  for (int r = 0; r < 4; r++)
#pragma unroll
    for (int j = 0; j < NBINS; j++) binacc[r][j] = 0.0f;

  // tile 0: inline loads + MFMA chain
  size_t bbase = (size_t)(b * 16 + t0) * 512 + lane;
  f32x4 acc0 = {0.f, 0.f, 0.f, 0.f};
#pragma unroll
  for (int kk = 0; kk < 8; kk++) {
    bf16x8 bh = *reinterpret_cast<const bf16x8*>(&canH[bbase + kk * 64]);
    bf16x8 bl = *reinterpret_cast<const bf16x8*>(&canL[bbase + kk * 64]);
    acc0 = __builtin_amdgcn_mfma_f32_16x16x32_bf16(ah[kk], bh, acc0, 0, 0, 0);
    acc0 = __builtin_amdgcn_mfma_f32_16x16x32_bf16(al[kk], bh, acc0, 0, 0, 0);
    acc0 = __builtin_amdgcn_mfma_f32_16x16x32_bf16(ah[kk], bl, acc0, 0, 0, 0);
  }
  // tile 1: prefetch before bins(tile 0) so load latency hides under exps
  bf16x8 bh1[8], bl1[8];
#pragma unroll
  for (int kk = 0; kk < 8; kk++) {
    bh1[kk] = *reinterpret_cast<const bf16x8*>(&canH[bbase + 512 + kk * 64]);
    bl1[kk] = *reinterpret_cast<const bf16x8*>(&canL[bbase + 512 + kk * 64]);
  }
  bins_acc(acc0, mk0, binacc);
  f32x4 acc1 = {0.f, 0.f, 0.f, 0.f};
#pragma unroll
  for (int kk = 0; kk < 8; kk++) {
    acc1 = __builtin_amdgcn_mfma_f32_16x16x32_bf16(ah[kk], bh1[kk], acc1, 0, 0, 0);
    acc1 = __builtin_amdgcn_mfma_f32_16x16x32_bf16(al[kk], bh1[kk], acc1, 0, 0, 0);
    acc1 = __builtin_amdgcn_mfma_f32_16x16x32_bf16(ah[kk], bl1[kk], acc1, 0, 0, 0);
  }
  bins_acc(acc1, mk1, binacc);

  // ---- reduce over the 16 t-cols (lq) held by this wave ----
#pragma unroll
  for (int r = 0; r < 4; r++)
#pragma unroll
    for (int j = 0; j < NBINS; j++) {
      float v = binacc[r][j];
      v += __shfl_xor(v, 1);
      v += __shfl_xor(v, 2);
      v += __shfl_xor(v, 4);
      v += __shfl_xor(v, 8);
      binacc[r][j] = v;
    }
  if (lq == 0) {
#pragma unroll
    for (int r = 0; r < 4; r++)
#pragma unroll
      for (int j = 0; j < NBINS; j++)
        partial[(wv * 16 + lk * 4 + r) * NBINS + j] = binacc[r][j];
  }
  __syncthreads();

  // combine the two tq halves -> 352 partials for (outb, ts)
  for (int idx = tid; idx < Q_ * NBINS; idx += 256) {
    int q = idx / NBINS;
    int j = idx - q * NBINS;
    int m = q >> 4, r16 = q & 15;
    float s = partial[((0 + m) * 16 + r16) * NBINS + j] +
              partial[((2 + m) * 16 + r16) * NBINS + j];
    psum[((size_t)(outb * 4 + ts)) * (Q_ * NBINS) + idx] = s;
  }
}

// ---------------------------------------------------------------------------
// finish_kernel: grid 64 (one block per b). Waves 0-1: qproj = rep_cur@W_att
// + b_att with 2 output dims/thread and unroll-8 (16 loads in flight --
// R11's serial-chain mistake had ~1 load in flight and cost 17us). Waves
// 2-3 concurrently: sum the 4 t-split psums, log-pool * word_atten *
// mask_hq -> lp_sm. Then pooled, 8 scores, masked softmax, tanh-dense,
// direct out[b] store. No atomics.
// ---------------------------------------------------------------------------
__global__ __launch_bounds__(256) void finish_kernel(
    const float* __restrict__ psum, const float* __restrict__ word_atten,
    const float* __restrict__ mask_hq, const float* __restrict__ rep,
    const float* __restrict__ rep_cur, const float* __restrict__ mask_session,
    const float* __restrict__ W_dense, const float* __restrict__ b_dense,
    const float* __restrict__ W_att, const float* __restrict__ b_att,
    float* __restrict__ out) {
  __shared__ float qproj[256];
  __shared__ float lp_sm[NB_ * Q_ * NBINS];  // 2816
  __shared__ float pooled_sm[NB_ * NBINS];   // 88
  __shared__ float scores_sm[NB_];

  int b = blockIdx.x;
  int tid = threadIdx.x;
  int wv = tid >> 6, lane = tid & 63;

  if (wv < 2) {
    // qproj: threads 0..127, two output dims each (tid, tid+128)
    const float* rc = rep_cur + b * D_;
    float a0 = b_att[tid], a1 = b_att[tid + 128];
#pragma unroll 8
    for (int k = 0; k < D_; k++) {
      float r = rc[k];
      a0 += r * W_att[k * D_ + tid];
      a1 += r * W_att[k * D_ + tid + 128];
    }
    qproj[tid] = a0;
    qproj[tid + 128] = a1;
  } else {
    // lp staging: 2816 items over 128 threads
    int t2 = tid - 128;
    for (int idx = t2; idx < NB_ * Q_ * NBINS; idx += 128) {
      int nn = idx / (Q_ * NBINS);
      int rem = idx - nn * (Q_ * NBINS);
      int q = rem / NBINS;
      int outb = b * NB_ + nn;
      const float* pp = psum + ((size_t)outb * 4) * (Q_ * NBINS) + rem;
      float s = pp[0] + pp[Q_ * NBINS] + pp[2 * Q_ * NBINS] +
                pp[3 * Q_ * NBINS];
      float wa = word_atten[outb * Q_ + q] * mask_hq[outb * Q_ + q];
      lp_sm[idx] = logf(fmaxf(s, 1e-10f)) * 0.01f * wa;
    }
  }
  __syncthreads();

  // pooled[nn][j] = sum_q lp
  if (tid < NB_ * NBINS) {
    int nn = tid / NBINS, j = tid - nn * NBINS;
    float s = 0.f;
#pragma unroll
    for (int q = 0; q < Q_; q++) s += lp_sm[(nn * Q_ + q) * NBINS + j];
    pooled_sm[tid] = s;
  }

  // scores: each wave does 2 of the 8 session blocks
  for (int nn = wv; nn < NB_; nn += 4) {
    const float* rp = rep + ((size_t)b * NB_ + nn) * D_;
    float4 r4 = reinterpret_cast<const float4*>(rp)[lane];
    float4 q4 = *reinterpret_cast<float4*>(&qproj[lane * 4]);
    float s = r4.x * q4.x + r4.y * q4.y + r4.z * q4.z + r4.w * q4.w;
#pragma unroll
    for (int off = 32; off > 0; off >>= 1) s += __shfl_down(s, off);
    if (lane == 0) scores_sm[nn] = s * 0.0625f;  // 1/sqrt(256)
  }
  __syncthreads();

  if (tid == 0) {
    float sc[NB_];
    float mx = -1e30f;
    for (int nn = 0; nn < NB_; nn++) {
      float s = (mask_session[b * NB_ + nn] > 0.f) ? scores_sm[nn] : -1e9f;
      sc[nn] = s;
      mx = fmaxf(mx, s);
    }
    float den = 0.f;
    for (int nn = 0; nn < NB_; nn++) {
      sc[nn] = __expf(sc[nn] - mx);
      den += sc[nn];
    }
    float invd = 1.0f / den;
    float res = 0.f;
    for (int nn = 0; nn < NB_; nn++) {
      float ms = mask_session[b * NB_ + nn];
      float pw = b_dense[0];
#pragma unroll
      for (int j = 0; j < NBINS; j++)
        pw += pooled_sm[nn * NBINS + j] * ms * W_dense[j];
      res += tanhf(pw) * sc[nn] * invd;
    }
    out[b] = res;
  }
}

// ---------------------------------------------------------------------------
// 3 dispatches: split (1024 blk), pool (2048 blk), finish (64 blk).
// ws: canH/L + hqH/L (32 MB) + psum (2.8 MB).
// ---------------------------------------------------------------------------
extern "C" void kernel_launch(void* const* d_in, const int* in_sizes, int n_in,
                              void* d_out, int out_size, void* d_ws,
                              size_t ws_size, hipStream_t stream) {
  const float* word_atten = (const float*)d_in[0];
  const float* hq = (const float*)d_in[1];
  const float* can = (const float*)d_in[2];
  const float* rep = (const float*)d_in[3];
  const float* rep_cur = (const float*)d_in[4];
  const float* mask_hq = (const float*)d_in[5];
  const float* mask_can = (const float*)d_in[6];
  const float* mask_session = (const float*)d_in[7];
  const float* W_dense = (const float*)d_in[8];
  const float* b_dense = (const float*)d_in[9];
  const float* W_att = (const float*)d_in[10];
  const float* b_att = (const float*)d_in[11];
  float* out = (float*)d_out;

  char* ws = (char*)d_ws;
  uint4* canH = (uint4*)(ws + CANH_OFF);
  uint4* canL = (uint4*)(ws + CANL_OFF);
  uint4* hqH = (uint4*)(ws + HQH_OFF);
  uint4* hqL = (uint4*)(ws + HQL_OFF);
  float* psum = (float*)(ws + PSUM_OFF);

  hipLaunchKernelGGL(split_kernel, dim3(1024), dim3(256), 0, stream, can, hq,
                     canH, canL, hqH, hqL);
  hipLaunchKernelGGL(pool_kernel, dim3(2048), dim3(256), 0, stream, hqH, hqL,
                     canH, canL, mask_can, psum);
  hipLaunchKernelGGL(finish_kernel, dim3(B_), dim3(256), 0, stream, psum,
                     word_atten, mask_hq, rep, rep_cur, mask_session, W_dense,
                     b_dense, W_att, b_att, out);
}